// Round 1
// baseline (176.270 us; speedup 1.0000x reference)
//
#include <hip/hip_runtime.h>

typedef __bf16 bf16_t;
typedef bf16_t bf16x8 __attribute__((ext_vector_type(8)));
typedef float f32x4 __attribute__((ext_vector_type(4)));

#define LDSW_BYTES 20480

// ws layout (bf16 element offsets). Each weight stored K-tiled:
// [K/32 tiles][Nout rows][40 bf16] (32 real k + 8 pad; 80B row stride).
#define OFF_W1A   0        // 8 * 256*40 = 81920
#define OFF_W1B   81920    // 8 * 512*40 = 163840
#define OFF_W2A   245760   // 8 * 256*40 = 81920
#define OFF_W2B   327680   // 8 *  64*40 = 20480
#define OFF_SMALL 348160   // 8 * 128*40 = 40960  (rows 0-63: Wb1, 64-127: Wb2a)
#define WS_BYTES  778240

__global__ __launch_bounds__(256) void cvt_w(
    const float* __restrict__ W1a, const float* __restrict__ W1b,
    const float* __restrict__ W2a, const float* __restrict__ W2b,
    const float* __restrict__ Wb1, const float* __restrict__ Wb2a,
    bf16_t* __restrict__ ws)
{
  int gid = blockIdx.x * 256 + threadIdx.x;
  const float* src; int Nout, local, wsoff, kkElems, rowoff = 0;
  if (gid < 65536)       { src=W1a;  Nout=256; local=gid;        wsoff=OFF_W1A;   kkElems=10240; }
  else if (gid < 196608) { src=W1b;  Nout=512; local=gid-65536;  wsoff=OFF_W1B;   kkElems=20480; }
  else if (gid < 262144) { src=W2a;  Nout=256; local=gid-196608; wsoff=OFF_W2A;   kkElems=10240; }
  else if (gid < 278528) { src=W2b;  Nout=64;  local=gid-262144; wsoff=OFF_W2B;   kkElems=2560;  }
  else if (gid < 294912) { src=Wb1;  Nout=64;  local=gid-278528; wsoff=OFF_SMALL; kkElems=5120;  }
  else if (gid < 311296) { src=Wb2a; Nout=64;  local=gid-294912; wsoff=OFF_SMALL; kkElems=5120; rowoff=64; }
  else return;
  int per_kk = Nout * 32;
  int kk = local / per_kk;
  int r  = local - kk * per_kk;
  int kw = r / Nout;          // k within 32-tile
  int n  = r - kw * Nout;     // output column (fastest -> coalesced reads)
  ws[wsoff + kk*kkElems + (n + rowoff)*40 + kw] = (bf16_t)src[(kk*32 + kw)*Nout + n];
}

// One wave computes 16 rows x (NT*16) cols, K=256 in 8 steps of 32.
// Weights staged cooperatively (256 threads) into double-buffered LDS.
template<int NT, int SB>
__device__ __forceinline__ void run_gemm(
    f32x4 (&acc)[NT], const bf16x8 (&aF)[8],
    const char* __restrict__ base, int kkStrideBytes,
    char (&lds)[2][LDSW_BYTES], int tid, int r16, int g)
{
  for (int off = tid*16; off < SB; off += 4096)
    *(float4*)(&lds[0][off]) = *(const float4*)(base + off);
  __syncthreads();
  #pragma unroll
  for (int kk = 0; kk < 8; ++kk) {
    const int cur = kk & 1;
    if (kk < 7) {
      const char* src = base + (kk + 1) * kkStrideBytes;
      for (int off = tid*16; off < SB; off += 4096)
        *(float4*)(&lds[cur ^ 1][off]) = *(const float4*)(src + off);
    }
    const char* buf = lds[cur];
    #pragma unroll
    for (int t = 0; t < NT; ++t) {
      bf16x8 b = *(const bf16x8*)(buf + (t*16 + r16)*80 + g*16);
      acc[t] = __builtin_amdgcn_mfma_f32_16x16x32_bf16(aF[kk], b, acc[t], 0, 0, 0);
    }
    __syncthreads();
  }
}

__global__ __launch_bounds__(256, 2) void qmix_main(
    const float* __restrict__ qv, const float* __restrict__ s,
    const bf16_t* __restrict__ ws,
    const float* __restrict__ b1a, const float* __restrict__ b1b,
    const float* __restrict__ b2a, const float* __restrict__ b2b,
    const float* __restrict__ bb1, const float* __restrict__ bb2a,
    const float* __restrict__ Wb2b, const float* __restrict__ bb2b,
    float* __restrict__ out)
{
  __shared__ __align__(16) char lds[2][LDSW_BYTES];
  const int tid  = threadIdx.x;
  const int wave = tid >> 6;
  const int lane = tid & 63;
  const int r16  = lane & 15;   // MFMA row (A) / col (B,D)
  const int g    = lane >> 4;   // k-group
  const int row0 = blockIdx.x * 64 + wave * 16;

  const char* wsb = (const char*)ws;

  // ---- s -> A fragments (16 rows x 256 k, bf16), reused by 4 GEMMs
  bf16x8 sA[8];
  {
    const float* srow = s + (size_t)(row0 + r16) * 256;
    #pragma unroll
    for (int kk = 0; kk < 8; ++kk) {
      float4 f0 = *(const float4*)(srow + kk*32 + g*8);
      float4 f1 = *(const float4*)(srow + kk*32 + g*8 + 4);
      bf16x8 a;
      a[0]=(bf16_t)f0.x; a[1]=(bf16_t)f0.y; a[2]=(bf16_t)f0.z; a[3]=(bf16_t)f0.w;
      a[4]=(bf16_t)f1.x; a[5]=(bf16_t)f1.y; a[6]=(bf16_t)f1.z; a[7]=(bf16_t)f1.w;
      sA[kk] = a;
    }
  }

  // ---- combined small GEMM: cols 0-63 = s@Wb1, cols 64-127 = s@Wb2a
  f32x4 accS[8];
  #pragma unroll
  for (int t = 0; t < 8; ++t) accS[t] = (f32x4)0.0f;
  run_gemm<8,10240>(accS, sA, wsb + OFF_SMALL*2, 10240, lds, tid, r16, g);

  float hidden[4][4];   // [u: qh-tile][e: row 4g+e]
  float b2r[4];
  {
    #pragma unroll
    for (int u = 0; u < 4; ++u) {
      float bias = bb1[u*16 + r16];
      #pragma unroll
      for (int e = 0; e < 4; ++e) hidden[u][e] = accS[u][e] + bias;  // b1
    }
    float t2[4] = {0.f, 0.f, 0.f, 0.f};
    #pragma unroll
    for (int u = 0; u < 4; ++u) {
      float bias = bb2a[u*16 + r16];
      float wv   = Wb2b[u*16 + r16];
      #pragma unroll
      for (int e = 0; e < 4; ++e) {
        float v = fmaxf(accS[4 + u][e] + bias, 0.f);
        t2[e] += v * wv;
      }
    }
    float bb2b0 = bb2b[0];
    #pragma unroll
    for (int e = 0; e < 4; ++e) {
      float v = t2[e];
      v += __shfl_xor(v, 1); v += __shfl_xor(v, 2);
      v += __shfl_xor(v, 4); v += __shfl_xor(v, 8);
      b2r[e] = v + bb2b0;   // scalar b2 per row
    }
  }

  // ---- GEMM1: h1 = relu(s@W1a + b1a), then transpose acc->A frags via LDS
  f32x4 acc1[16];
  #pragma unroll
  for (int t = 0; t < 16; ++t) acc1[t] = (f32x4)0.0f;
  run_gemm<16,20480>(acc1, sA, wsb + OFF_W1A*2, 20480, lds, tid, r16, g);

  bf16x8 hA[8];
  {
    char* H = &lds[wave >> 1][0] + (wave & 1) * 8448;  // 16 rows x 528B, wave-private
    #pragma unroll
    for (int t = 0; t < 16; ++t) {
      float bias = b1a[t*16 + r16];
      #pragma unroll
      for (int e = 0; e < 4; ++e) {
        float v = fmaxf(acc1[t][e] + bias, 0.f);
        *(bf16_t*)(H + (4*g + e)*528 + (t*16 + r16)*2) = (bf16_t)v;
      }
    }
    #pragma unroll
    for (int kk = 0; kk < 8; ++kk)
      hA[kk] = *(const bf16x8*)(H + r16*528 + kk*64 + g*16);
    __syncthreads();
  }

  // ---- GEMM1b: w1 = abs(h1@W1b + b1b) in 4 col-chunks, folded into hidden
  #pragma unroll 1
  for (int c = 0; c < 4; ++c) {
    f32x4 accW[8];
    #pragma unroll
    for (int t = 0; t < 8; ++t) accW[t] = (f32x4)0.0f;
    run_gemm<8,10240>(accW, hA, wsb + OFF_W1B*2 + c*10240, 40960, lds, tid, r16, g);
    #pragma unroll
    for (int tt = 0; tt < 8; ++tt) {
      int a = c*2 + (tt >> 2);     // agent index = col/64
      int u = tt & 3;              // qh tile = (col%64)/16
      float bias = b1b[c*128 + tt*16 + r16];
      #pragma unroll
      for (int e = 0; e < 4; ++e) {
        float w1v = fabsf(accW[tt][e] + bias);
        float qq  = qv[(size_t)(row0 + 4*g + e) * 8 + a];
        hidden[u][e] += qq * w1v;
      }
    }
  }

  // elu
  #pragma unroll
  for (int u = 0; u < 4; ++u)
    #pragma unroll
    for (int e = 0; e < 4; ++e) {
      float h = hidden[u][e];
      hidden[u][e] = h > 0.f ? h : (__expf(h) - 1.f);
    }

  // ---- GEMM2: h2 = relu(s@W2a + b2a), transpose to A frags
  #pragma unroll
  for (int t = 0; t < 16; ++t) acc1[t] = (f32x4)0.0f;
  run_gemm<16,20480>(acc1, sA, wsb + OFF_W2A*2, 20480, lds, tid, r16, g);
  {
    char* H = &lds[wave >> 1][0] + (wave & 1) * 8448;
    #pragma unroll
    for (int t = 0; t < 16; ++t) {
      float bias = b2a[t*16 + r16];
      #pragma unroll
      for (int e = 0; e < 4; ++e) {
        float v = fmaxf(acc1[t][e] + bias, 0.f);
        *(bf16_t*)(H + (4*g + e)*528 + (t*16 + r16)*2) = (bf16_t)v;
      }
    }
    #pragma unroll
    for (int kk = 0; kk < 8; ++kk)
      hA[kk] = *(const bf16x8*)(H + r16*528 + kk*64 + g*16);
    __syncthreads();
  }

  // ---- GEMM2b: w2 = abs(h2@W2b + b2b)
  f32x4 accV[4];
  #pragma unroll
  for (int t = 0; t < 4; ++t) accV[t] = (f32x4)0.0f;
  run_gemm<4,5120>(accV, hA, wsb + OFF_W2B*2, 5120, lds, tid, r16, g);

  // ---- q_total = hidden . w2 + b2
  float tq[4] = {0.f, 0.f, 0.f, 0.f};
  #pragma unroll
  for (int u = 0; u < 4; ++u) {
    float bias = b2b[u*16 + r16];
    #pragma unroll
    for (int e = 0; e < 4; ++e) {
      float w2v = fabsf(accV[u][e] + bias);
      tq[e] += hidden[u][e] * w2v;
    }
  }
  #pragma unroll
  for (int e = 0; e < 4; ++e) {
    float v = tq[e];
    v += __shfl_xor(v, 1); v += __shfl_xor(v, 2);
    v += __shfl_xor(v, 4); v += __shfl_xor(v, 8);
    if (r16 == 0) out[row0 + 4*g + e] = v + b2r[e];
  }
}

extern "C" void kernel_launch(void* const* d_in, const int* in_sizes, int n_in,
                              void* d_out, int out_size, void* d_ws, size_t ws_size,
                              hipStream_t stream) {
  const float* q    = (const float*)d_in[0];
  const float* s    = (const float*)d_in[1];
  const float* W1a  = (const float*)d_in[2];
  const float* b1a  = (const float*)d_in[3];
  const float* W1b  = (const float*)d_in[4];
  const float* b1b  = (const float*)d_in[5];
  const float* W2a  = (const float*)d_in[6];
  const float* b2a  = (const float*)d_in[7];
  const float* W2b  = (const float*)d_in[8];
  const float* b2b  = (const float*)d_in[9];
  const float* Wb1  = (const float*)d_in[10];
  const float* bb1  = (const float*)d_in[11];
  const float* Wb2a = (const float*)d_in[12];
  const float* bb2a = (const float*)d_in[13];
  const float* Wb2b = (const float*)d_in[14];
  const float* bb2b = (const float*)d_in[15];
  bf16_t* ws = (bf16_t*)d_ws;
  float* out = (float*)d_out;

  int N = in_sizes[0] / 8;        // 65536 rows
  int nblocks = N / 64;           // 64 rows per block

  cvt_w<<<1216, 256, 0, stream>>>(W1a, W1b, W2a, W2b, Wb1, Wb2a, ws);
  qmix_main<<<nblocks, 256, 0, stream>>>(q, s, ws, b1a, b1b, b2a, b2b,
                                         bb1, bb2a, Wb2b, bb2b, out);
}

// Round 2
// 114.269 us; speedup vs baseline: 1.5426x; 1.5426x over previous
//
#include <hip/hip_runtime.h>

typedef __bf16 bf16_t;
typedef bf16_t bf16x8 __attribute__((ext_vector_type(8)));
typedef bf16_t bf16x4 __attribute__((ext_vector_type(4)));
typedef bf16_t bf16x2 __attribute__((ext_vector_type(2)));
typedef float f32x4 __attribute__((ext_vector_type(4)));

#define MFMA __builtin_amdgcn_mfma_f32_16x16x32_bf16
#define SWZ(row, off) ((off) ^ (((row) & 7) << 4))

#define OFF_W1AT   0
#define OFF_W2AT   65536
#define OFF_W1BT   131072
#define OFF_SMALLT 262144
#define OFF_W2BT   294912
#define OFF_W2OUT  622592ul
#define OFF_B1ROW  9011200ul
#define OFF_B2OUT  17399808ul

__device__ __forceinline__ bf16x8 cvt8(float4 a, float4 b) {
  bf16x8 v;
  v[0]=(bf16_t)a.x; v[1]=(bf16_t)a.y; v[2]=(bf16_t)a.z; v[3]=(bf16_t)a.w;
  v[4]=(bf16_t)b.x; v[5]=(bf16_t)b.y; v[6]=(bf16_t)b.z; v[7]=(bf16_t)b.w;
  return v;
}

__global__ __launch_bounds__(256) void cvt_wT(
    const float* __restrict__ W1a, const float* __restrict__ W2a,
    const float* __restrict__ W1b, const float* __restrict__ Wb1,
    const float* __restrict__ Wb2a, const float* __restrict__ W2b,
    bf16_t* __restrict__ ws)
{
  int gid = blockIdx.x * 256 + threadIdx.x;
  const float* src; int base, nout;
  if (gid < 65536)       { src = W1a;  base = 0;      nout = 256; }
  else if (gid < 131072) { src = W2a;  base = 65536;  nout = 256; }
  else if (gid < 262144) { src = W1b;  base = 131072; nout = 512; }
  else if (gid < 278528) { src = Wb1;  base = 262144; nout = 64;  }
  else if (gid < 294912) { src = Wb2a; base = 278528; nout = 64;  }
  else                   { src = W2b;  base = 294912; nout = 64;  }
  int local = gid - base, col = local >> 8, k = local & 255;
  ws[gid] = (bf16_t)src[k * nout + col];
}

__global__ __launch_bounds__(512) void qmix_k1(
    const float* __restrict__ s, const bf16_t* __restrict__ ws,
    const float* __restrict__ b2a, const float* __restrict__ b2b,
    const float* __restrict__ bb1, const float* __restrict__ bb2a,
    const float* __restrict__ Wb2b, const float* __restrict__ bb2b,
    bf16_t* __restrict__ w2out, bf16_t* __restrict__ b1row,
    float* __restrict__ b2out)
{
  __shared__ __align__(16) char ldsV[64 * 512];
  __shared__ __align__(16) char sT[2][16 * 512];
  __shared__ __align__(16) char h2T[16 * 512];
  __shared__ float b2part[4][16];

  const int tid = threadIdx.x, wave = tid >> 6, lane = tid & 63;
  const int r16 = lane & 15, g = lane >> 4;
  const int row0 = blockIdx.x * 128;
  const int srow = tid >> 5, sc = tid & 31;

  bf16x8 aW[2][8], aSm[8];
  {
    const bf16_t* w2aT = ws + OFF_W2AT;
    const bf16_t* smT  = ws + OFF_SMALLT;
    #pragma unroll
    for (int t = 0; t < 2; ++t) {
      int col = (wave + t * 8) * 16 + r16;
      #pragma unroll
      for (int kk = 0; kk < 8; ++kk)
        aW[t][kk] = *(const bf16x8*)(w2aT + col * 256 + kk * 32 + g * 8);
    }
    int scol = wave * 16 + r16;
    #pragma unroll
    for (int kk = 0; kk < 8; ++kk)
      aSm[kk] = *(const bf16x8*)(smT + scol * 256 + kk * 32 + g * 8);
  }
  {
    const char* src = (const char*)(ws + OFF_W2BT);
    for (int c = tid; c < 2048; c += 512) {
      int col = c >> 5, o = (c & 31) * 16;
      *(float4*)(&ldsV[col * 512 + SWZ(col, o)]) = *(const float4*)(src + c * 16);
    }
  }
  {
    const float* p = s + (size_t)(row0 + srow) * 256 + sc * 8;
    float4 f0 = *(const float4*)p, f1 = *(const float4*)(p + 4);
    *(bf16x8*)(&sT[0][srow * 512 + SWZ(srow, sc * 16)]) = cvt8(f0, f1);
  }
  __syncthreads();

  for (int rt = 0; rt < 8; ++rt) {
    const int cur = rt & 1;
    const int rowt = row0 + rt * 16;
    float4 pf0, pf1;
    if (rt < 7) {
      const float* p = s + (size_t)(rowt + 16 + srow) * 256 + sc * 8;
      pf0 = *(const float4*)p; pf1 = *(const float4*)(p + 4);
    }
    f32x4 acc0 = (f32x4)0.f, acc1 = (f32x4)0.f, accS = (f32x4)0.f;
    #pragma unroll
    for (int kk = 0; kk < 8; ++kk) {
      bf16x8 sB = *(const bf16x8*)(&sT[cur][r16 * 512 + SWZ(r16, kk * 64 + g * 16)]);
      acc0 = MFMA(aW[0][kk], sB, acc0, 0, 0, 0);
      acc1 = MFMA(aW[1][kk], sB, acc1, 0, 0, 0);
      accS = MFMA(aSm[kk], sB, accS, 0, 0, 0);
    }
    if (wave < 4) {
      float4 bb = *(const float4*)(bb1 + wave * 16 + 4 * g);
      bf16x4 o;
      o[0]=(bf16_t)(accS[0]+bb.x); o[1]=(bf16_t)(accS[1]+bb.y);
      o[2]=(bf16_t)(accS[2]+bb.z); o[3]=(bf16_t)(accS[3]+bb.w);
      *(bf16x4*)(b1row + (size_t)(rowt + r16) * 64 + wave * 16 + 4 * g) = o;
    } else {
      float4 ba = *(const float4*)(bb2a + (wave - 4) * 16 + 4 * g);
      float4 wv = *(const float4*)(Wb2b + (wave - 4) * 16 + 4 * g);
      float part = fmaxf(accS[0]+ba.x,0.f)*wv.x + fmaxf(accS[1]+ba.y,0.f)*wv.y
                 + fmaxf(accS[2]+ba.z,0.f)*wv.z + fmaxf(accS[3]+ba.w,0.f)*wv.w;
      part += __shfl_xor(part, 16); part += __shfl_xor(part, 32);
      if (lane < 16) b2part[wave - 4][r16] = part;
    }
    {
      float4 b0 = *(const float4*)(b2a + wave * 16 + 4 * g);
      bf16x4 h;
      h[0]=(bf16_t)fmaxf(acc0[0]+b0.x,0.f); h[1]=(bf16_t)fmaxf(acc0[1]+b0.y,0.f);
      h[2]=(bf16_t)fmaxf(acc0[2]+b0.z,0.f); h[3]=(bf16_t)fmaxf(acc0[3]+b0.w,0.f);
      *(bf16x4*)(&h2T[r16 * 512 + SWZ(r16, wave * 32 + 8 * g)]) = h;
      float4 b1_ = *(const float4*)(b2a + 128 + wave * 16 + 4 * g);
      bf16x4 h2;
      h2[0]=(bf16_t)fmaxf(acc1[0]+b1_.x,0.f); h2[1]=(bf16_t)fmaxf(acc1[1]+b1_.y,0.f);
      h2[2]=(bf16_t)fmaxf(acc1[2]+b1_.z,0.f); h2[3]=(bf16_t)fmaxf(acc1[3]+b1_.w,0.f);
      *(bf16x4*)(&h2T[r16 * 512 + SWZ(r16, 256 + wave * 32 + 8 * g)]) = h2;
    }
    __syncthreads();
    if (rt < 7)
      *(bf16x8*)(&sT[cur ^ 1][srow * 512 + SWZ(srow, sc * 16)]) = cvt8(pf0, pf1);
    if (wave < 4) {
      f32x4 accV = (f32x4)0.f;
      const int vcol = wave * 16 + r16;
      #pragma unroll
      for (int kk = 0; kk < 8; ++kk) {
        bf16x8 hB = *(const bf16x8*)(&h2T[r16 * 512 + SWZ(r16, kk * 64 + g * 16)]);
        bf16x8 aV = *(const bf16x8*)(&ldsV[vcol * 512 + SWZ(vcol, kk * 64 + g * 16)]);
        accV = MFMA(aV, hB, accV, 0, 0, 0);
      }
      float4 bv = *(const float4*)(b2b + wave * 16 + 4 * g);
      bf16x4 o;
      o[0]=(bf16_t)fabsf(accV[0]+bv.x); o[1]=(bf16_t)fabsf(accV[1]+bv.y);
      o[2]=(bf16_t)fabsf(accV[2]+bv.z); o[3]=(bf16_t)fabsf(accV[3]+bv.w);
      *(bf16x4*)(w2out + (size_t)(rowt + r16) * 64 + wave * 16 + 4 * g) = o;
    } else if (wave == 7 && lane < 16) {
      b2out[rowt + lane] = b2part[0][lane] + b2part[1][lane]
                         + b2part[2][lane] + b2part[3][lane] + bb2b[0];
    }
    __syncthreads();
  }
}

__global__ __launch_bounds__(512) void qmix_k2(
    const float* __restrict__ s, const float* __restrict__ q,
    const bf16_t* __restrict__ ws,
    const float* __restrict__ b1a, const float* __restrict__ b1b,
    const bf16_t* __restrict__ w2in, const bf16_t* __restrict__ b1row,
    const float* __restrict__ b2in, float* __restrict__ out)
{
  __shared__ __align__(16) char ldsA[128 * 512];
  __shared__ __align__(16) char sT[2][16 * 512];
  __shared__ __align__(16) char h1T[16 * 512];
  __shared__ __align__(16) char slab[8 * 4096];

  const int tid = threadIdx.x, wave = tid >> 6, lane = tid & 63;
  const int r16 = lane & 15, g = lane >> 4;
  const int row0 = blockIdx.x * 128;
  const int srow = tid >> 5, sc = tid & 31;

  bf16x8 aB[4][8], aA[8];
  {
    const bf16_t* w1bT = ws + OFF_W1BT;
    #pragma unroll
    for (int tt = 0; tt < 4; ++tt)
      #pragma unroll
      for (int kk = 0; kk < 8; ++kk)
        aB[tt][kk] = *(const bf16x8*)(w1bT + (wave * 64 + tt * 16 + r16) * 256 + kk * 32 + g * 8);
    #pragma unroll
    for (int kk = 0; kk < 8; ++kk)
      aA[kk] = *(const bf16x8*)(ws + (wave * 16 + r16) * 256 + kk * 32 + g * 8);
  }
  {
    const char* srcA = (const char*)(ws + 128 * 256);
    for (int c = tid; c < 4096; c += 512) {
      int col = c >> 5, o = (c & 31) * 16;
      *(float4*)(&ldsA[col * 512 + SWZ(col, o)]) = *(const float4*)(srcA + c * 16);
    }
  }
  {
    const float* p = s + (size_t)(row0 + srow) * 256 + sc * 8;
    float4 f0 = *(const float4*)p, f1 = *(const float4*)(p + 4);
    *(bf16x8*)(&sT[0][srow * 512 + SWZ(srow, sc * 16)]) = cvt8(f0, f1);
  }
  __syncthreads();

  for (int rt = 0; rt < 8; ++rt) {
    const int cur = rt & 1;
    const int rowt = row0 + rt * 16;
    float4 pf0, pf1;
    if (rt < 7) {
      const float* p = s + (size_t)(rowt + 16 + srow) * 256 + sc * 8;
      pf0 = *(const float4*)p; pf1 = *(const float4*)(p + 4);
    }
    float qa = q[(size_t)(rowt + r16) * 8 + wave];
    f32x4 acc0 = (f32x4)0.f, acc1 = (f32x4)0.f;
    const int lcol = wave * 16 + r16;
    #pragma unroll
    for (int kk = 0; kk < 8; ++kk) {
      bf16x8 sB = *(const bf16x8*)(&sT[cur][r16 * 512 + SWZ(r16, kk * 64 + g * 16)]);
      acc0 = MFMA(aA[kk], sB, acc0, 0, 0, 0);
      bf16x8 aL = *(const bf16x8*)(&ldsA[lcol * 512 + SWZ(lcol, kk * 64 + g * 16)]);
      acc1 = MFMA(aL, sB, acc1, 0, 0, 0);
    }
    {
      float4 b0 = *(const float4*)(b1a + wave * 16 + 4 * g);
      bf16x4 h;
      h[0]=(bf16_t)fmaxf(acc0[0]+b0.x,0.f); h[1]=(bf16_t)fmaxf(acc0[1]+b0.y,0.f);
      h[2]=(bf16_t)fmaxf(acc0[2]+b0.z,0.f); h[3]=(bf16_t)fmaxf(acc0[3]+b0.w,0.f);
      *(bf16x4*)(&h1T[r16 * 512 + SWZ(r16, wave * 32 + 8 * g)]) = h;
      float4 b1_ = *(const float4*)(b1a + 128 + wave * 16 + 4 * g);
      bf16x4 h2;
      h2[0]=(bf16_t)fmaxf(acc1[0]+b1_.x,0.f); h2[1]=(bf16_t)fmaxf(acc1[1]+b1_.y,0.f);
      h2[2]=(bf16_t)fmaxf(acc1[2]+b1_.z,0.f); h2[3]=(bf16_t)fmaxf(acc1[3]+b1_.w,0.f);
      *(bf16x4*)(&h1T[r16 * 512 + SWZ(r16, 256 + wave * 32 + 8 * g)]) = h2;
    }
    __syncthreads();
    if (rt < 7)
      *(bf16x8*)(&sT[cur ^ 1][srow * 512 + SWZ(srow, sc * 16)]) = cvt8(pf0, pf1);
    f32x4 a2[4];
    #pragma unroll
    for (int tt = 0; tt < 4; ++tt) a2[tt] = (f32x4)0.f;
    #pragma unroll
    for (int kk = 0; kk < 8; ++kk) {
      bf16x8 hB = *(const bf16x8*)(&h1T[r16 * 512 + SWZ(r16, kk * 64 + g * 16)]);
      #pragma unroll
      for (int tt = 0; tt < 4; ++tt)
        a2[tt] = MFMA(aB[tt][kk], hB, a2[tt], 0, 0, 0);
    }
    #pragma unroll
    for (int tt = 0; tt < 4; ++tt) {
      float4 bb = *(const float4*)(b1b + wave * 64 + tt * 16 + 4 * g);
      f32x4 v;
      v[0]=qa*fabsf(a2[tt][0]+bb.x); v[1]=qa*fabsf(a2[tt][1]+bb.y);
      v[2]=qa*fabsf(a2[tt][2]+bb.z); v[3]=qa*fabsf(a2[tt][3]+bb.w);
      *(f32x4*)(&slab[wave * 4096 + r16 * 256 + SWZ(r16, (tt * 16 + 4 * g) * 4)]) = v;
    }
    __syncthreads();
    {
      int row = srow, qp = sc * 2;
      float s0 = 0.f, s1 = 0.f;
      #pragma unroll
      for (int w = 0; w < 8; ++w) {
        float2 sv = *(const float2*)(&slab[w * 4096 + row * 256 + SWZ(row, qp * 4)]);
        s0 += sv.x; s1 += sv.y;
      }
      bf16x2 bv = *(const bf16x2*)(b1row + (size_t)(rowt + row) * 64 + qp);
      float h0 = s0 + (float)bv[0], h1 = s1 + (float)bv[1];
      h0 = h0 > 0.f ? h0 : (__expf(h0) - 1.f);
      h1 = h1 > 0.f ? h1 : (__expf(h1) - 1.f);
      bf16x2 wv = *(const bf16x2*)(w2in + (size_t)(rowt + row) * 64 + qp);
      float dot = h0 * (float)wv[0] + h1 * (float)wv[1];
      dot += __shfl_xor(dot, 1); dot += __shfl_xor(dot, 2);
      dot += __shfl_xor(dot, 4); dot += __shfl_xor(dot, 8);
      dot += __shfl_xor(dot, 16);
      if (sc == 0) out[rowt + row] = dot + b2in[rowt + row];
    }
  }
}

extern "C" void kernel_launch(void* const* d_in, const int* in_sizes, int n_in,
                              void* d_out, int out_size, void* d_ws, size_t ws_size,
                              hipStream_t stream) {
  const float* q    = (const float*)d_in[0];
  const float* s    = (const float*)d_in[1];
  const float* W1a  = (const float*)d_in[2];
  const float* b1a  = (const float*)d_in[3];
  const float* W1b  = (const float*)d_in[4];
  const float* b1b  = (const float*)d_in[5];
  const float* W2a  = (const float*)d_in[6];
  const float* b2a  = (const float*)d_in[7];
  const float* W2b  = (const float*)d_in[8];
  const float* b2b  = (const float*)d_in[9];
  const float* Wb1  = (const float*)d_in[10];
  const float* bb1  = (const float*)d_in[11];
  const float* Wb2a = (const float*)d_in[12];
  const float* bb2a = (const float*)d_in[13];
  const float* Wb2b = (const float*)d_in[14];
  const float* bb2b = (const float*)d_in[15];
  bf16_t* ws = (bf16_t*)d_ws;
  float* out = (float*)d_out;

  bf16_t* w2out = (bf16_t*)((char*)d_ws + OFF_W2OUT);
  bf16_t* b1row = (bf16_t*)((char*)d_ws + OFF_B1ROW);
  float*  b2out = (float*)((char*)d_ws + OFF_B2OUT);

  int N  = in_sizes[0] / 8;
  int nb = N / 128;

  cvt_wT<<<1216, 256, 0, stream>>>(W1a, W2a, W1b, Wb1, Wb2a, W2b, ws);
  qmix_k1<<<nb, 512, 0, stream>>>(s, ws, b2a, b2b, bb1, bb2a, Wb2b, bb2b,
                                  w2out, b1row, b2out);
  qmix_k2<<<nb, 512, 0, stream>>>(s, q, ws, b1a, b1b, w2out, b1row,
                                  b2out, out);
}